// Round 1
// baseline (8531.136 us; speedup 1.0000x reference)
//
#include <hip/hip_runtime.h>
#include <math.h>

#define NB 16
#define WD 128

// ---------------- split input into data / clipped mask ----------------
__global__ void split_k(const float* __restrict__ x, float* __restrict__ data,
                        float* __restrict__ mask) {
  const int HW = 256 * 128;
  int i = blockIdx.x * 256 + threadIdx.x;
  if (i >= NB * HW) return;
  int n = i / HW, rem = i % HW;
  data[i] = x[(size_t)(n * 2) * HW + rem];
  float mv = x[(size_t)(n * 2 + 1) * HW + rem];
  mask[i] = fminf(fmaxf(mv, 0.f), 1.f);
}

// ---------------- zero helper (graph-capture-safe memset) ----------------
__global__ void zero_k(float* __restrict__ p, int n) {
  int i = blockIdx.x * 256 + threadIdx.x;
  if (i < n) p[i] = 0.f;
}

// ---------------- mask 3x3 sum (pad=1) -> scale + mask_next ----------------
__global__ void maskscale_k(const float* __restrict__ m, float* __restrict__ scale,
                            float* __restrict__ mnext, int H, float Ci) {
  int i = blockIdx.x * 256 + threadIdx.x;
  int tot = NB * H * WD;
  if (i >= tot) return;
  int x = i % WD;
  int t = i / WD;
  int y = t % H;
  int n = t / H;
  const float* mn_ = m + (size_t)n * H * WD;
  float s = 0.f;
#pragma unroll
  for (int dy = -1; dy <= 1; dy++) {
    int yy = y + dy;
#pragma unroll
    for (int dx = -1; dx <= 1; dx++) {
      int xx = x + dx;
      float v = 1.0f;  // pad with 1.0 per reference
      if (yy >= 0 && yy < H && xx >= 0 && xx < WD) v = mn_[yy * WD + xx];
      s += v;
    }
  }
  float valid = Ci * s;
  float sc = (9.0f * Ci) / fmaxf(valid, 1.0f);
  scale[i] = sc;
  mnext[i] = (valid <= 0.0f) ? 0.f : 1.f;
}

// ---------------- direct 3x3 conv, partial-conv epilogue, BN stats ----------------
// block: 256 threads = 16 x-threads (2 cols each) x 16 co-threads (1 co, 8 rows each)
// grid: x = (WD/32)*(H/8) spatial tiles, y = Co/16, z = n
__global__ __launch_bounds__(256) void conv_k(
    const float* __restrict__ h, const float* __restrict__ m,
    const float* __restrict__ w, const float* __restrict__ b,
    const float* __restrict__ scale, const float* __restrict__ mnext,
    float* __restrict__ y, float* __restrict__ sums, int Ci, int Co, int H) {
  const int tid = threadIdx.x;
  const int lx = tid & 15;   // x-thread
  const int j = tid >> 4;    // co-thread
  const int ntx = WD / 32;
  const int xt = blockIdx.x % ntx;
  const int yt = blockIdx.x / ntx;
  const int x0 = xt * 32, y0 = yt * 8;
  const int co = blockIdx.y * 16 + j;
  const int n = blockIdx.z;

  __shared__ __align__(16) float tile[2][10][36];

  const float* hn = h + (size_t)n * Ci * H * WD;
  const float* mn_ = m + (size_t)n * H * WD;

  float acc[8][2];
#pragma unroll
  for (int r = 0; r < 8; r++) { acc[r][0] = 0.f; acc[r][1] = 0.f; }

  auto load_tile = [&](int ci, int buf) {
    for (int idx = tid; idx < 340; idx += 256) {
      int rr = idx / 34, cc = idx % 34;
      int yy = y0 - 1 + rr, xx = x0 - 1 + cc;
      float v = 0.f;  // hm is zero-padded
      if (yy >= 0 && yy < H && xx >= 0 && xx < WD)
        v = hn[((size_t)ci * H + yy) * WD + xx] * mn_[yy * WD + xx];
      tile[buf][rr][cc] = v;
    }
  };

  load_tile(0, 0);
  __syncthreads();

  const float* wco = w + (size_t)co * Ci * 9;
  const int c0 = 2 * lx;

  for (int ci = 0; ci < Ci; ci++) {
    int buf = ci & 1;
    if (ci + 1 < Ci) load_tile(ci + 1, buf ^ 1);

    float wr[9];
#pragma unroll
    for (int t = 0; t < 9; t++) wr[t] = wco[ci * 9 + t];

    const float* base = &tile[buf][0][0];
    float2 a0a = *(const float2*)(base + 0 * 36 + c0);
    float2 a0b = *(const float2*)(base + 0 * 36 + c0 + 2);
    float2 a1a = *(const float2*)(base + 1 * 36 + c0);
    float2 a1b = *(const float2*)(base + 1 * 36 + c0 + 2);
#pragma unroll
    for (int r = 0; r < 8; r++) {
      float2 a2a = *(const float2*)(base + (r + 2) * 36 + c0);
      float2 a2b = *(const float2*)(base + (r + 2) * 36 + c0 + 2);
      acc[r][0] += a0a.x * wr[0] + a0a.y * wr[1] + a0b.x * wr[2]
                 + a1a.x * wr[3] + a1a.y * wr[4] + a1b.x * wr[5]
                 + a2a.x * wr[6] + a2a.y * wr[7] + a2b.x * wr[8];
      acc[r][1] += a0a.y * wr[0] + a0b.x * wr[1] + a0b.y * wr[2]
                 + a1a.y * wr[3] + a1b.x * wr[4] + a1b.y * wr[5]
                 + a2a.y * wr[6] + a2b.x * wr[7] + a2b.y * wr[8];
      a0a = a1a; a0b = a1b; a1a = a2a; a1b = a2b;
    }
    __syncthreads();
  }

  // epilogue: partial-conv scale + bias, zero where no valid, write, BN stats
  float lsum = 0.f, lsq = 0.f;
  const float bco = b[co];
  const size_t ybase = (size_t)(n * Co + co) * H * WD;
#pragma unroll
  for (int r = 0; r < 8; r++) {
    int yy = y0 + r;
    int xx = x0 + c0;
    int si = (n * H + yy) * WD + xx;
    float2 sc = *(const float2*)&scale[si];
    float2 mx = *(const float2*)&mnext[si];
    float v0 = (acc[r][0] * sc.x + bco) * mx.x;
    float v1 = (acc[r][1] * sc.y + bco) * mx.y;
    *(float2*)&y[ybase + (size_t)yy * WD + xx] = make_float2(v0, v1);
    lsum += v0 + v1;
    lsq += v0 * v0 + v1 * v1;
  }
#pragma unroll
  for (int off = 8; off >= 1; off >>= 1) {
    lsum += __shfl_down(lsum, off, 16);
    lsq += __shfl_down(lsq, off, 16);
  }
  if (lx == 0) {
    atomicAdd(&sums[co], lsum);
    atomicAdd(&sums[Co + co], lsq);
  }
}

// ---------------- BN finalize: per-channel scale/shift ----------------
__global__ void bnfin_k(const float* __restrict__ sums, const float* __restrict__ g,
                        const float* __restrict__ be, float* __restrict__ ab, int Co,
                        float invCount) {
  int c = blockIdx.x * 64 + threadIdx.x;
  if (c >= Co) return;
  float mean = sums[c] * invCount;
  float var = sums[Co + c] * invCount - mean * mean;
  float rs = rsqrtf(var + 1e-5f);
  float a = g[c] * rs;
  ab[c] = a;
  ab[Co + c] = be[c] - mean * a;
}

// ---------------- BN + ReLU + (2,1) maxpool ----------------
__global__ void bnpool_k(const float* __restrict__ y, const float* __restrict__ ab,
                         float* __restrict__ out, int Co, int H) {
  int Hp = H / 2;
  int i = blockIdx.x * 256 + threadIdx.x;
  int tot = NB * Co * Hp * (WD / 4);
  if (i >= tot) return;
  int xq = i % (WD / 4);
  int t = i / (WD / 4);
  int yo = t % Hp; t /= Hp;
  int c = t % Co;
  int n = t / Co;
  float a = ab[c], sh = ab[Co + c];
  size_t b0 = ((size_t)(n * Co + c) * H + 2 * yo) * WD + xq * 4;
  float4 v0 = *(const float4*)&y[b0];
  float4 v1 = *(const float4*)&y[b0 + WD];
  float4 o;
  o.x = fmaxf(fmaxf(v0.x * a + sh, v1.x * a + sh), 0.f);
  o.y = fmaxf(fmaxf(v0.y * a + sh, v1.y * a + sh), 0.f);
  o.z = fmaxf(fmaxf(v0.z * a + sh, v1.z * a + sh), 0.f);
  o.w = fmaxf(fmaxf(v0.w * a + sh, v1.w * a + sh), 0.f);
  *(float4*)&out[((size_t)(n * Co + c) * Hp + yo) * WD + xq * 4] = o;
}

// ---------------- mask (2,1) maxpool ----------------
__global__ void maskpool_k(const float* __restrict__ mn, float* __restrict__ mp, int H) {
  int Hp = H / 2;
  int i = blockIdx.x * 256 + threadIdx.x;
  int tot = NB * Hp * WD;
  if (i >= tot) return;
  int x = i % WD;
  int t = i / WD;
  int yo = t % Hp;
  int n = t / Hp;
  mp[i] = fmaxf(mn[((size_t)n * H + 2 * yo) * WD + x],
                mn[((size_t)n * H + 2 * yo + 1) * WD + x]);
}

// ---------------- global average pool -> feat (16,640) ----------------
__global__ void feat_k(const float* __restrict__ h, float* __restrict__ feat) {
  int bc = blockIdx.x;  // 16*640 blocks
  int c = bc % 640;
  int n = bc / 640;
  const float* p = h + (size_t)(n * 640 + c) * 16 * 128;
  float s = 0.f;
  for (int k = threadIdx.x; k < 2048; k += 256) s += p[k];
#pragma unroll
  for (int off = 32; off >= 1; off >>= 1) s += __shfl_down(s, off, 64);
  __shared__ float red[4];
  if ((threadIdx.x & 63) == 0) red[threadIdx.x >> 6] = s;
  __syncthreads();
  if (threadIdx.x == 0)
    feat[n * 640 + c] = (red[0] + red[1] + red[2] + red[3]) * (1.f / 2048.f);
}

// ---------------- fc1 (640->256) + relu ----------------
__global__ void fc1_k(const float* __restrict__ feat, const float* __restrict__ fw,
                      const float* __restrict__ fb, float* __restrict__ z1) {
  int n = blockIdx.x;      // 16
  int o = threadIdx.x;     // 256
  const float* f = feat + n * 640;
  const float* wr = fw + o * 640;
  float s = fb[o];
  for (int k = 0; k < 640; k++) s += f[k] * wr[k];
  z1[n * 256 + o] = fmaxf(s, 0.f);
}

// ---------------- fc2 (256->128) + relu + head + sigmoid ----------------
__global__ void fc2h_k(const float* __restrict__ z1, const float* __restrict__ fw2,
                       const float* __restrict__ fb2, const float* __restrict__ hw,
                       const float* __restrict__ hb, float* __restrict__ out) {
  int n = blockIdx.x;    // 16
  int o = threadIdx.x;   // 128
  const float* zr = z1 + n * 256;
  const float* wr = fw2 + o * 256;
  float s = fb2[o];
  for (int k = 0; k < 256; k++) s += zr[k] * wr[k];
  s = fmaxf(s, 0.f) * hw[o];
#pragma unroll
  for (int off = 32; off >= 1; off >>= 1) s += __shfl_down(s, off, 64);
  __shared__ float red[2];
  if ((threadIdx.x & 63) == 0) red[threadIdx.x >> 6] = s;
  __syncthreads();
  if (threadIdx.x == 0) {
    float t = red[0] + red[1] + hb[0];
    out[n] = 1.f / (1.f + expf(-t));
  }
}

extern "C" void kernel_launch(void* const* d_in, const int* in_sizes, int n_in,
                              void* d_out, int out_size, void* d_ws, size_t ws_size,
                              hipStream_t stream) {
  const float* x = (const float*)d_in[0];
  const float* wgt[4] = {(const float*)d_in[1], (const float*)d_in[5],
                         (const float*)d_in[9], (const float*)d_in[13]};
  const float* bias[4] = {(const float*)d_in[2], (const float*)d_in[6],
                          (const float*)d_in[10], (const float*)d_in[14]};
  const float* gam[4] = {(const float*)d_in[3], (const float*)d_in[7],
                         (const float*)d_in[11], (const float*)d_in[15]};
  const float* bet[4] = {(const float*)d_in[4], (const float*)d_in[8],
                         (const float*)d_in[12], (const float*)d_in[16]};
  const float* fw1 = (const float*)d_in[17];
  const float* fb1 = (const float*)d_in[18];
  const float* fw2 = (const float*)d_in[19];
  const float* fb2 = (const float*)d_in[20];
  const float* hw = (const float*)d_in[21];
  const float* hb = (const float*)d_in[22];

  float* ws = (float*)d_ws;
  float* bufY = ws;                       // 41,943,040
  float* bufA = ws + 41943040;            // 20,971,520
  float* mask0 = ws + 62914560;           // 524,288
  float* mask1 = mask0 + 524288;          // 524,288
  float* scaleB = mask1 + 524288;         // 524,288
  float* mnextB = scaleB + 524288;        // 524,288
  float* sums = mnextB + 524288;          // 1,280
  float* bnab = sums + 1280;              // 1,280
  float* feat = bnab + 1280;              // 10,240
  float* z1 = feat + 10240;               // 4,096

  // split input
  {
    int tot = NB * 256 * 128;
    split_k<<<(tot + 255) / 256, 256, 0, stream>>>(x, bufA, mask0);
  }

  const int Ci[4] = {1, 80, 160, 320};
  const int Co[4] = {80, 160, 320, 640};
  const int Hs[4] = {256, 128, 64, 32};

  float* mcur = mask0;
  float* mnxt = mask1;
  for (int s = 0; s < 4; s++) {
    int H = Hs[s];
    int tot = NB * H * WD;
    maskscale_k<<<(tot + 255) / 256, 256, 0, stream>>>(mcur, scaleB, mnextB, H,
                                                       (float)Ci[s]);
    zero_k<<<(2 * Co[s] + 255) / 256, 256, 0, stream>>>(sums, 2 * Co[s]);
    dim3 grid((WD / 32) * (H / 8), Co[s] / 16, NB);
    conv_k<<<grid, 256, 0, stream>>>(bufA, mcur, wgt[s], bias[s], scaleB, mnextB,
                                     bufY, sums, Ci[s], Co[s], H);
    bnfin_k<<<(Co[s] + 63) / 64, 64, 0, stream>>>(sums, gam[s], bet[s], bnab, Co[s],
                                                  1.0f / (NB * (float)H * WD));
    int totp = NB * Co[s] * (H / 2) * (WD / 4);
    bnpool_k<<<(totp + 255) / 256, 256, 0, stream>>>(bufY, bnab, bufA, Co[s], H);
    int totm = NB * (H / 2) * WD;
    maskpool_k<<<(totm + 255) / 256, 256, 0, stream>>>(mnextB, mnxt, H);
    float* tmp = mcur; mcur = mnxt; mnxt = tmp;
  }

  feat_k<<<16 * 640, 256, 0, stream>>>(bufA, feat);
  fc1_k<<<16, 256, 0, stream>>>(feat, fw1, fb1, z1);
  fc2h_k<<<16, 128, 0, stream>>>(z1, fw2, fb2, hw, hb, (float*)d_out);
}

// Round 2
// 2372.895 us; speedup vs baseline: 3.5952x; 3.5952x over previous
//
#include <hip/hip_runtime.h>
#include <math.h>

#define NB 16
#define WD 128

typedef __bf16 bf16_t;
typedef __bf16 bf16x8 __attribute__((ext_vector_type(8)));
typedef __bf16 bf16x4 __attribute__((ext_vector_type(4)));
typedef float f32x4 __attribute__((ext_vector_type(4)));

// ---------------- zero helper ----------------
__global__ void zero_k(float* __restrict__ p, int n) {
  int i = blockIdx.x * 256 + threadIdx.x;
  if (i < n) p[i] = 0.f;
}

// ---------------- split input into data / clipped mask ----------------
__global__ void split_k(const float* __restrict__ x, float* __restrict__ data,
                        float* __restrict__ mask) {
  const int HW = 256 * 128;
  int i = blockIdx.x * 256 + threadIdx.x;
  if (i >= NB * HW) return;
  int n = i / HW, rem = i % HW;
  data[i] = x[(size_t)(n * 2) * HW + rem];
  float mv = x[(size_t)(n * 2 + 1) * HW + rem];
  mask[i] = fminf(fmaxf(mv, 0.f), 1.f);
}

// ---------------- mask 3x3 sum (pad=1) -> scale + mask_next ----------------
__global__ void maskscale_k(const float* __restrict__ m, float* __restrict__ scale,
                            float* __restrict__ mnext, int H, float Ci) {
  int i = blockIdx.x * 256 + threadIdx.x;
  int tot = NB * H * WD;
  if (i >= tot) return;
  int x = i % WD;
  int t = i / WD;
  int y = t % H;
  int n = t / H;
  const float* mn_ = m + (size_t)n * H * WD;
  float s = 0.f;
#pragma unroll
  for (int dy = -1; dy <= 1; dy++) {
    int yy = y + dy;
#pragma unroll
    for (int dx = -1; dx <= 1; dx++) {
      int xx = x + dx;
      float v = 1.0f;
      if (yy >= 0 && yy < H && xx >= 0 && xx < WD) v = mn_[yy * WD + xx];
      s += v;
    }
  }
  float valid = Ci * s;
  float sc = (9.0f * Ci) / fmaxf(valid, 1.0f);
  scale[i] = sc;
  mnext[i] = (valid <= 0.0f) ? 0.f : 1.f;
}

// ---------------- mask (2,1) maxpool ----------------
__global__ void maskpool_k(const float* __restrict__ mn, float* __restrict__ mp, int H) {
  int Hp = H / 2;
  int i = blockIdx.x * 256 + threadIdx.x;
  int tot = NB * Hp * WD;
  if (i >= tot) return;
  int x = i % WD;
  int t = i / WD;
  int yo = t % Hp;
  int n = t / Hp;
  mp[i] = fmaxf(mn[((size_t)n * H + 2 * yo) * WD + x],
                mn[((size_t)n * H + 2 * yo + 1) * WD + x]);
}

// ---------------- stage-1 direct conv (Ci=1), NHWC bf16 out ----------------
// block 256 = 128 co-lanes x 2 x; grid (64, 256, 16)
__global__ void pconv1_k(const float* __restrict__ data, const float* __restrict__ mask,
                         const float* __restrict__ w, const float* __restrict__ b,
                         const float* __restrict__ scale, const float* __restrict__ mnext,
                         bf16_t* __restrict__ y) {
  int co = threadIdx.x & 127;
  int xi = threadIdx.x >> 7;
  int x = blockIdx.x * 2 + xi;
  int yy = blockIdx.y;
  int n = blockIdx.z;
  const int H = 256;
  if (co >= 80) return;
  const float* dn = data + (size_t)n * H * WD;
  const float* mn = mask + (size_t)n * H * WD;
  float s = 0.f;
#pragma unroll
  for (int dy = 0; dy < 3; dy++) {
    int yv = yy - 1 + dy;
#pragma unroll
    for (int dx = 0; dx < 3; dx++) {
      int xv = x - 1 + dx;
      if (yv >= 0 && yv < H && xv >= 0 && xv < WD)
        s += w[co * 9 + dy * 3 + dx] * dn[yv * WD + xv] * mn[yv * WD + xv];
    }
  }
  int p = (n * H + yy) * WD + x;
  float v = (s * scale[p] + b[co]) * mnext[p];
  y[(size_t)p * 80 + co] = (bf16_t)v;
}

// ---------------- BN stats over NHWC bf16 (stage 1) ----------------
__global__ void bnstats_k(const bf16_t* __restrict__ y, float* __restrict__ sums,
                          int C, int P) {
  int c = threadIdx.x;  // blockDim 128
  if (c >= C) return;
  float s = 0.f, q = 0.f;
  for (int p = blockIdx.x; p < P; p += gridDim.x) {
    float v = (float)y[(size_t)p * C + c];
    s += v;
    q += v * v;
  }
  atomicAdd(&sums[c], s);
  atomicAdd(&sums[C + c], q);
}

// ---------------- weight transform: w[co][ci][3][3] fp32 -> wt2 bf16 ----------------
// wt2 index: ((tap*NCB + cb)*Co_pad + co)*32 + q   (ci = cb*32+q), zero padded
__global__ void wtrans_k(const float* __restrict__ w, bf16_t* __restrict__ wt2,
                         int Ci, int Co, int NCB, int Co_pad) {
  int idx = blockIdx.x * 256 + threadIdx.x;
  int total = 9 * NCB * Co_pad * 32;
  if (idx >= total) return;
  int q = idx & 31;
  int co = (idx >> 5) % Co_pad;
  int cb = ((idx >> 5) / Co_pad) % NCB;
  int tap = (idx >> 5) / (Co_pad * NCB);
  int ci = cb * 32 + q;
  float v = 0.f;
  if (co < Co && ci < Ci) v = w[((size_t)co * Ci + ci) * 9 + tap];
  wt2[idx] = (bf16_t)v;
}

// ---------------- MFMA implicit-GEMM 3x3 conv (stages 2-4) ----------------
// grid: (Co_pad/128, NB*H); block 256 = 4 waves (2M x 2N), wave tile 64x64
// xmT: bf16 [NB][H+2][132][Ci_pad], masked input, zero borders
// out y: bf16 NHWC [NB][H][WD][Co]
__global__ __launch_bounds__(256) void convmfma_k(
    const bf16_t* __restrict__ xmT, const bf16_t* __restrict__ wt2,
    const float* __restrict__ bias, const float* __restrict__ scale,
    const float* __restrict__ mnext, bf16_t* __restrict__ y,
    float* __restrict__ sums, int H, int Ci_pad, int NCB, int Co, int Co_pad) {
  __shared__ bf16_t tile[3 * 144 * 32];  // 27,648 B
  const int tid = threadIdx.x;
  const int lane = tid & 63;
  const int wave = tid >> 6;
  const int wm = wave >> 1, wn = wave & 1;
  const int g = lane >> 4;   // 0..3 (k-group)
  const int ln = lane & 15;  // frag row/col
  const int coTile = blockIdx.x * 128;
  const int bx = blockIdx.y;  // n*H + y
  const int n = bx / H, yrow = bx % H;

  f32x4 acc[4][4];
#pragma unroll
  for (int mf = 0; mf < 4; mf++)
#pragma unroll
    for (int nf = 0; nf < 4; nf++) acc[mf][nf] = (f32x4)(0.f);

  const int colL = lane >> 2;  // 0..15
  const int q16 = lane & 3;    // 16B part within 64B ci-chunk
  const size_t rowStrideG = (size_t)132 * Ci_pad;
  const size_t gRow0 = ((size_t)n * (H + 2) + yrow) * rowStrideG;

  for (int cb = 0; cb < NCB; ++cb) {
    __syncthreads();
    // stage 3 rows x 144 cols x 32 ci into LDS (27 chunks of 16 cols)
    for (int c = wave; c < 27; c += 4) {
      int row = c / 9, c16m = (c % 9) * 16;
      int col = c16m + colL;
      const bf16_t* gsrc = xmT + gRow0 + (size_t)row * rowStrideG +
                           (size_t)col * Ci_pad + cb * 32 + q16 * 8;
      bf16_t* ldst = &tile[(row * 144 + c16m) * 32];
      __builtin_amdgcn_global_load_lds(
          (__attribute__((address_space(1))) void*)gsrc,
          (__attribute__((address_space(3))) void*)ldst, 16, 0, 0);
    }
    __syncthreads();

#pragma unroll
    for (int tap = 0; tap < 9; ++tap) {
      const int dy = tap / 3, dxo = tap % 3;
      bf16x8 a[4];
      const size_t abase =
          (((size_t)tap * NCB + cb) * Co_pad + coTile + wm * 64 + ln) * 32 + g * 8;
#pragma unroll
      for (int mf = 0; mf < 4; ++mf)
        a[mf] = *(const bf16x8*)(wt2 + abase + (size_t)mf * 16 * 32);
      bf16x8 bb[4];
#pragma unroll
      for (int nf = 0; nf < 4; ++nf) {
        int colx = wn * 64 + nf * 16 + ln + dxo;
        bb[nf] = *(const bf16x8*)(tile + (dy * 144 + colx) * 32 + g * 8);
      }
#pragma unroll
      for (int mf = 0; mf < 4; ++mf)
#pragma unroll
        for (int nf = 0; nf < 4; ++nf)
          acc[mf][nf] =
              __builtin_amdgcn_mfma_f32_16x16x32_bf16(a[mf], bb[nf], acc[mf][nf], 0, 0, 0);
    }
  }

  // epilogue: partial-conv scale + bias + mask, write NHWC bf16, BN stats
  const int pixBase = (n * H + yrow) * WD;
  float scl[4], msk[4];
#pragma unroll
  for (int nf = 0; nf < 4; ++nf) {
    int x = wn * 64 + nf * 16 + ln;
    scl[nf] = scale[pixBase + x];
    msk[nf] = mnext[pixBase + x];
  }
#pragma unroll
  for (int mf = 0; mf < 4; ++mf) {
    if (coTile + wm * 64 + mf * 16 >= Co) continue;  // padded frag
    int coB = coTile + wm * 64 + mf * 16 + g * 4;
    f32x4 bias4 = *(const f32x4*)&bias[coB];
    f32x4 s4 = (f32x4)(0.f), q4 = (f32x4)(0.f);
#pragma unroll
    for (int nf = 0; nf < 4; ++nf) {
      int x = wn * 64 + nf * 16 + ln;
      f32x4 v;
      bf16x4 o;
#pragma unroll
      for (int r = 0; r < 4; ++r) {
        v[r] = (acc[mf][nf][r] * scl[nf] + bias4[r]) * msk[nf];
        o[r] = (bf16_t)v[r];
      }
      *(bf16x4*)&y[(size_t)(pixBase + x) * Co + coB] = o;
      s4 += v;
      q4 += v * v;
    }
#pragma unroll
    for (int off = 1; off < 16; off <<= 1) {
#pragma unroll
      for (int r = 0; r < 4; ++r) {
        float ts = s4[r], tq = q4[r];
        s4[r] = ts + __shfl_xor(ts, off);
        q4[r] = tq + __shfl_xor(tq, off);
      }
    }
    if (ln == 0) {
#pragma unroll
      for (int r = 0; r < 4; ++r) {
        atomicAdd(&sums[coB + r], s4[r]);
        atomicAdd(&sums[Co + coB + r], q4[r]);
      }
    }
  }
}

// ---------------- BN finalize ----------------
__global__ void bnfin_k(const float* __restrict__ sums, const float* __restrict__ g,
                        const float* __restrict__ be, float* __restrict__ ab, int Co,
                        float invCount) {
  int c = blockIdx.x * 64 + threadIdx.x;
  if (c >= Co) return;
  float mean = sums[c] * invCount;
  float var = sums[Co + c] * invCount - mean * mean;
  float rs = rsqrtf(var + 1e-5f);
  float a = g[c] * rs;
  ab[c] = a;
  ab[Co + c] = be[c] - mean * a;
}

// ---------------- BN + ReLU + (2,1) pool + mask -> padded NHWC bf16 xmT ----------------
__global__ void bnpool_k(const bf16_t* __restrict__ y, const float* __restrict__ ab,
                         const float* __restrict__ mp, bf16_t* __restrict__ out, int C,
                         int Cp, int H) {
  int Hp = H / 2;
  int Cq = C / 8;
  int tid = blockIdx.x * 256 + threadIdx.x;
  int total = NB * Hp * WD * Cq;
  if (tid >= total) return;
  int c8 = tid % Cq;
  int t = tid / Cq;
  int x = t % WD;
  t /= WD;
  int yo = t % Hp;
  int n = t / Hp;
  int c = c8 * 8;
  const bf16_t* p0 = y + ((size_t)((n * H + 2 * yo) * WD + x)) * C + c;
  const bf16_t* p1 = p0 + (size_t)WD * C;
  float mpv = mp[(n * Hp + yo) * WD + x];
  bf16x8 v0 = *(const bf16x8*)p0;
  bf16x8 v1 = *(const bf16x8*)p1;
  bf16x8 o;
#pragma unroll
  for (int j = 0; j < 8; ++j) {
    float a = ab[c + j], sh = ab[C + c + j];
    float f0 = (float)v0[j] * a + sh;
    float f1 = (float)v1[j] * a + sh;
    o[j] = (bf16_t)(fmaxf(fmaxf(f0, f1), 0.f) * mpv);
  }
  *(bf16x8*)&out[(((size_t)n * (Hp + 2) + yo + 1) * 132 + x + 1) * Cp + c] = o;
}

// ---------------- stage-4: BN + ReLU + pool + global mean -> feat ----------------
// grid (16, 5, 16), block 128
__global__ void bnfeat_k(const bf16_t* __restrict__ y, const float* __restrict__ ab,
                         float* __restrict__ feat) {
  int n = blockIdx.x, cc = blockIdx.y, yo = blockIdx.z;
  int c = cc * 128 + threadIdx.x;  // C = 640
  float a = ab[c], sh = ab[640 + c];
  float s = 0.f;
  for (int x = 0; x < WD; ++x) {
    size_t p0 = ((size_t)(n * 32 + 2 * yo) * WD + x) * 640 + c;
    float v0 = (float)y[p0] * a + sh;
    float v1 = (float)y[p0 + (size_t)WD * 640] * a + sh;
    s += fmaxf(fmaxf(v0, v1), 0.f);
  }
  atomicAdd(&feat[n * 640 + c], s * (1.f / 2048.f));
}

// ---------------- fc1 (640->256) + relu ----------------
__global__ void fc1_k(const float* __restrict__ feat, const float* __restrict__ fw,
                      const float* __restrict__ fb, float* __restrict__ z1) {
  int n = blockIdx.x;
  int o = threadIdx.x;
  const float* f = feat + n * 640;
  const float* wr = fw + o * 640;
  float s = fb[o];
  for (int k = 0; k < 640; k++) s += f[k] * wr[k];
  z1[n * 256 + o] = fmaxf(s, 0.f);
}

// ---------------- fc2 (256->128) + relu + head + sigmoid ----------------
__global__ void fc2h_k(const float* __restrict__ z1, const float* __restrict__ fw2,
                       const float* __restrict__ fb2, const float* __restrict__ hw,
                       const float* __restrict__ hb, float* __restrict__ out) {
  int n = blockIdx.x;
  int o = threadIdx.x;
  const float* zr = z1 + n * 256;
  const float* wr = fw2 + o * 256;
  float s = fb2[o];
  for (int k = 0; k < 256; k++) s += zr[k] * wr[k];
  s = fmaxf(s, 0.f) * hw[o];
#pragma unroll
  for (int off = 32; off >= 1; off >>= 1) s += __shfl_down(s, off, 64);
  __shared__ float red[2];
  if ((threadIdx.x & 63) == 0) red[threadIdx.x >> 6] = s;
  __syncthreads();
  if (threadIdx.x == 0) {
    float t = red[0] + red[1] + hb[0];
    out[n] = 1.f / (1.f + expf(-t));
  }
}

extern "C" void kernel_launch(void* const* d_in, const int* in_sizes, int n_in,
                              void* d_out, int out_size, void* d_ws, size_t ws_size,
                              hipStream_t stream) {
  const float* x = (const float*)d_in[0];
  const float* wgt[4] = {(const float*)d_in[1], (const float*)d_in[5],
                         (const float*)d_in[9], (const float*)d_in[13]};
  const float* bias[4] = {(const float*)d_in[2], (const float*)d_in[6],
                          (const float*)d_in[10], (const float*)d_in[14]};
  const float* gam[4] = {(const float*)d_in[3], (const float*)d_in[7],
                         (const float*)d_in[11], (const float*)d_in[15]};
  const float* bet[4] = {(const float*)d_in[4], (const float*)d_in[8],
                         (const float*)d_in[12], (const float*)d_in[16]};
  const float* fw1 = (const float*)d_in[17];
  const float* fb1 = (const float*)d_in[18];
  const float* fw2 = (const float*)d_in[19];
  const float* fb2 = (const float*)d_in[20];
  const float* hw = (const float*)d_in[21];
  const float* hb = (const float*)d_in[22];

  char* base = (char*)d_ws;
  size_t off = 0;
  auto alloc = [&](size_t bytes) {
    char* p = base + off;
    off += (bytes + 255) & ~(size_t)255;
    return p;
  };
  bf16_t* bufY = (bf16_t*)alloc(83886080);           // 41,943,040 bf16
  const size_t xmtElems = 26365952;                  // incl. 8192 elem slack
  bf16_t* xmT0 = (bf16_t*)alloc(xmtElems * 2);
  bf16_t* xmT1 = (bf16_t*)alloc(xmtElems * 2);
  bf16_t* wt2 = (bf16_t*)alloc(3686400);
  float* data = (float*)alloc(2097152);
  float* mask0 = (float*)alloc(2097152);
  float* mask1 = (float*)alloc(2097152);
  float* scaleB = (float*)alloc(2097152);
  float* mnextB = (float*)alloc(2097152);
  float* sums = (float*)alloc(5120);
  float* bnab = (float*)alloc(5120);
  float* feat = (float*)alloc(40960);
  float* z1 = (float*)alloc(16384);

  // zero xmT0+xmT1 (contiguous) and feat
  {
    int nf = (int)(xmtElems * 2 * 2 / 4);  // both buffers as floats
    zero_k<<<(nf + 255) / 256, 256, 0, stream>>>((float*)xmT0, nf);
    zero_k<<<40, 256, 0, stream>>>(feat, 10240);
  }

  // split input
  split_k<<<(NB * 256 * 128 + 255) / 256, 256, 0, stream>>>(x, data, mask0);

  // ---------- stage 1 (direct, Ci=1, Co=80, H=256) ----------
  {
    int H = 256;
    int tot = NB * H * WD;
    maskscale_k<<<(tot + 255) / 256, 256, 0, stream>>>(mask0, scaleB, mnextB, H, 1.0f);
    zero_k<<<1, 256, 0, stream>>>(sums, 160);
    pconv1_k<<<dim3(64, 256, 16), 256, 0, stream>>>(data, mask0, wgt[0], bias[0],
                                                    scaleB, mnextB, bufY);
    bnstats_k<<<512, 128, 0, stream>>>(bufY, sums, 80, NB * H * WD);
    bnfin_k<<<2, 64, 0, stream>>>(sums, gam[0], bet[0], bnab, 80,
                                  1.0f / (NB * (float)H * WD));
    maskpool_k<<<(NB * (H / 2) * WD + 255) / 256, 256, 0, stream>>>(mnextB, mask1, H);
    int totp = NB * (H / 2) * WD * (80 / 8);
    bnpool_k<<<(totp + 255) / 256, 256, 0, stream>>>(bufY, bnab, mask1, xmT0, 80, 96, H);
  }

  // ---------- stages 2-4 (MFMA implicit GEMM) ----------
  const int CiS[3] = {80, 160, 320};
  const int CipS[3] = {96, 160, 320};
  const int NCBS[3] = {3, 5, 10};
  const int CoS[3] = {160, 320, 640};
  const int CopS[3] = {256, 384, 640};
  const int HS[3] = {128, 64, 32};
  bf16_t* xin[3] = {xmT0, xmT1, xmT0};
  bf16_t* xout[3] = {xmT1, xmT0, nullptr};
  float* mIn[3] = {mask1, mask0, mask1};
  float* mOut[3] = {mask0, mask1, nullptr};

  for (int s = 0; s < 3; ++s) {
    int H = HS[s], Ci = CiS[s], Cip = CipS[s], NCB = NCBS[s], Co = CoS[s],
        Cop = CopS[s];
    int wtot = 9 * NCB * Cop * 32;
    wtrans_k<<<(wtot + 255) / 256, 256, 0, stream>>>(wgt[s + 1], wt2, Ci, Co, NCB, Cop);
    int tot = NB * H * WD;
    maskscale_k<<<(tot + 255) / 256, 256, 0, stream>>>(mIn[s], scaleB, mnextB, H,
                                                       (float)Ci);
    zero_k<<<(2 * Co + 255) / 256, 256, 0, stream>>>(sums, 2 * Co);
    convmfma_k<<<dim3(Cop / 128, NB * H), 256, 0, stream>>>(
        xin[s], wt2, bias[s + 1], scaleB, mnextB, bufY, sums, H, Cip, NCB, Co, Cop);
    bnfin_k<<<(Co + 63) / 64, 64, 0, stream>>>(sums, gam[s + 1], bet[s + 1], bnab, Co,
                                               1.0f / (NB * (float)H * WD));
    if (s < 2) {
      maskpool_k<<<(NB * (H / 2) * WD + 255) / 256, 256, 0, stream>>>(mnextB, mOut[s], H);
      int totp = NB * (H / 2) * WD * (Co / 8);
      bnpool_k<<<(totp + 255) / 256, 256, 0, stream>>>(bufY, bnab, mOut[s], xout[s], Co,
                                                       Co, H);
    } else {
      bnfeat_k<<<dim3(16, 5, 16), 128, 0, stream>>>(bufY, bnab, feat);
    }
  }

  fc1_k<<<16, 256, 0, stream>>>(feat, fw1, fb1, z1);
  fc2h_k<<<16, 128, 0, stream>>>(z1, fw2, fb2, hw, hb, (float*)d_out);
}